// Round 13
// baseline (154.404 us; speedup 1.0000x reference)
//
#include <hip/hip_runtime.h>
#include <math.h>

typedef __attribute__((ext_vector_type(4))) int i32x4;
typedef __attribute__((ext_vector_type(4))) float f32x4;

#define GLOAD_LDS16(g, l)                                          \
  __builtin_amdgcn_global_load_lds(                                \
      (const __attribute__((address_space(1))) void*)(g),          \
      (__attribute__((address_space(3))) void*)(l), 16, 0, 0)

// ---------------- weight quantization (merged) ----------------
__global__ void kWabs(const float* __restrict__ w1, const float* __restrict__ w2,
                      double* __restrict__ part) {
  const bool second = blockIdx.x >= 256;
  const float* w = second ? w2 : w1;
  const int n = second ? 262144 : 524288;
  int t = (blockIdx.x & 255) * 256 + threadIdx.x;
  double s = 0.0;
  for (int i = t; i < n; i += 65536) s += (double)fabsf(w[i]);
#pragma unroll
  for (int m = 32; m >= 1; m >>= 1) s += __shfl_xor(s, m);
  __shared__ double sd[4];
  int lane = threadIdx.x & 63, wid = threadIdx.x >> 6;
  if (lane == 0) sd[wid] = s;
  __syncthreads();
  if (threadIdx.x == 0) part[blockIdx.x] = (sd[0] + sd[1]) + (sd[2] + sd[3]);
}

__global__ void kWfin(const double* __restrict__ part, float* __restrict__ wsv) {
  const double* p = part + blockIdx.x * 256;
  const double n = (blockIdx.x == 0) ? 524288.0 : 262144.0;
  double s = p[threadIdx.x];
#pragma unroll
  for (int m = 32; m >= 1; m >>= 1) s += __shfl_xor(s, m);
  __shared__ double sd[4];
  int lane = threadIdx.x & 63, wid = threadIdx.x >> 6;
  if (lane == 0) sd[wid] = s;
  __syncthreads();
  if (threadIdx.x == 0) {
    double tot = (sd[0] + sd[1]) + (sd[2] + sd[3]);
    wsv[blockIdx.x] = fmaxf((float)(tot / n), 1e-5f);  // = 1/scale_w
  }
}

__global__ void kWq(const float* __restrict__ w1, const float* __restrict__ w2,
                    const float* __restrict__ wsv,
                    char* __restrict__ wq1, char* __restrict__ wq2) {
  const bool second = blockIdx.x >= 2048;
  const float* w = second ? w2 : w1;
  char* wq = second ? wq2 : wq1;
  const float scale = 1.0f / wsv[second ? 1 : 0];
  int i = (second ? blockIdx.x - 2048 : blockIdx.x) * 256 + threadIdx.x;
  float q = fminf(fmaxf(rintf(w[i] * scale), -1.0f), 1.0f);
  wq[i] = (char)(int)q;
}

// ---------------- kFused1: RMSNorm+quant (paired rows) + BitLinear GEMM1 -------------
// Phase A: 8 waves x 8 rows, processed as 4 PAIRS — two independent reduce chains in
// flight per wave to hide shfl latency. Phase B: barrier-free K-loop, 2-deep B-prefetch.
__global__ __launch_bounds__(512, 4) void kFused1(
    const float* __restrict__ prior, const float* __restrict__ evid,
    const char* __restrict__ Wq, const float* __restrict__ biasG,
    const float* __restrict__ wS,
    char* __restrict__ XqOut, float* __restrict__ rActOut) {
  __shared__ __align__(16) union {
    char Ap[65536];                                  // 64 rows x 1024 i8, byte e^((r&7)<<4)
    struct { float sq[64][8]; float mx[64][8]; } ep; // epilogue overlay (post-barrier)
  } u;
  __shared__ float rowSc[64];
  __shared__ float biasS[512];

  const int tid = threadIdx.x;
  const int lane = tid & 63;
  const int wn = tid >> 6;   // wave 0..7
  const int lr = lane & 15;
  const int kg = lane >> 4;  // 0..3
  const size_t row0 = (size_t)blockIdx.x * 64;

  biasS[tid] = biasG[tid];

  // ---- Phase A: per-row RMSNorm + absmax quant, rows in pairs ----
  {
    const int lc = lane * 4;
    const float* pp = prior + (row0 + wn * 8) * 512 + lc;
    const float* pe = evid + (row0 + wn * 8) * 512 + lc;
    f32x4 x[2][4];
#pragma unroll
    for (int r = 0; r < 2; ++r) {
      x[r][0] = *(const f32x4*)(pp + r * 512);
      x[r][1] = *(const f32x4*)(pp + r * 512 + 256);
      x[r][2] = *(const f32x4*)(pe + r * 512);
      x[r][3] = *(const f32x4*)(pe + r * 512 + 256);
    }
#pragma unroll
    for (int pr = 0; pr < 4; ++pr) {
      f32x4 y[2][4];
      if (pr < 3) {  // prefetch next pair (in flight during both reduces)
#pragma unroll
        for (int r = 0; r < 2; ++r) {
          const float* np = pp + (pr * 2 + 2 + r) * 512;
          const float* ne = pe + (pr * 2 + 2 + r) * 512;
          y[r][0] = *(const f32x4*)np; y[r][1] = *(const f32x4*)(np + 256);
          y[r][2] = *(const f32x4*)ne; y[r][3] = *(const f32x4*)(ne + 256);
        }
      }
      float ss[2] = {0.f, 0.f}, mx[2] = {0.f, 0.f};
#pragma unroll
      for (int r = 0; r < 2; ++r)
#pragma unroll
        for (int v = 0; v < 4; ++v)
#pragma unroll
          for (int i = 0; i < 4; ++i) {
            float f = x[r][v][i];
            ss[r] += f * f; mx[r] = fmaxf(mx[r], fabsf(f));
          }
#pragma unroll
      for (int m = 32; m >= 1; m >>= 1) {  // two independent chains interleaved
        ss[0] += __shfl_xor(ss[0], m); ss[1] += __shfl_xor(ss[1], m);
        mx[0] = fmaxf(mx[0], __shfl_xor(mx[0], m)); mx[1] = fmaxf(mx[1], __shfl_xor(mx[1], m));
      }
#pragma unroll
      for (int r = 0; r < 2; ++r) {
        const float inv = 1.0f / sqrtf(ss[r] * (1.0f / 1024.0f) + 1e-6f);
        const float amax = fmaxf(mx[r] * inv, 1e-5f);
        const float s = 127.0f / amax;
        int pk[4];
#pragma unroll
        for (int v = 0; v < 4; ++v) {
          int p = 0;
#pragma unroll
          for (int i = 0; i < 4; ++i) {
            int qi = (int)fminf(fmaxf(rintf(x[r][v][i] * inv * s), -128.0f), 127.0f);
            p |= (qi & 255) << (8 * i);
          }
          pk[v] = p;
        }
        const int rw = wn * 8 + pr * 2 + r;
        const int base = rw * 1024 + (lc ^ ((rw & 7) << 4));
        *(int*)&u.Ap[base] = pk[0];
        *(int*)&u.Ap[base + 256] = pk[1];
        *(int*)&u.Ap[base + 512] = pk[2];
        *(int*)&u.Ap[base + 768] = pk[3];
        if (lane == 0) rowSc[rw] = amax / 127.0f;
      }
      if (pr < 3) {
#pragma unroll
        for (int r = 0; r < 2; ++r)
#pragma unroll
          for (int v = 0; v < 4; ++v) x[r][v] = y[r][v];
      }
    }
  }

  // ---- Phase B: barrier-free K-loop, 2-deep B-prefetch ring ----
  i32x4 acc[4][4];
#pragma unroll
  for (int a = 0; a < 4; ++a)
#pragma unroll
    for (int b = 0; b < 4; ++b) acc[a][b] = (i32x4){0, 0, 0, 0};

  const char* gBl = Wq + (size_t)(wn * 64 + lr) * 1024 + kg * 16;
  i32x4 bf0[4], bf1[4];
#pragma unroll
  for (int fn = 0; fn < 4; ++fn) {
    bf0[fn] = *(const i32x4*)(gBl + fn * 16384);        // kt=0
    bf1[fn] = *(const i32x4*)(gBl + 64 + fn * 16384);   // kt=1
  }

  __syncthreads();  // A-panel ds_writes visible to all waves

  const int aswz = (lr & 7) << 4;
#pragma unroll
  for (int kt = 0; kt < 16; ++kt) {
    i32x4(&bfc)[4] = (kt & 1) ? bf1 : bf0;  // static with full unroll
    const int acol = (kt * 64 + kg * 16) ^ aswz;
    i32x4 af[4];
#pragma unroll
    for (int fm = 0; fm < 4; ++fm)
      af[fm] = *(const i32x4*)&u.Ap[(fm * 16 + lr) * 1024 + acol];
#pragma unroll
    for (int fn = 0; fn < 4; ++fn)
#pragma unroll
      for (int fm = 0; fm < 4; ++fm)
        acc[fm][fn] = __builtin_amdgcn_mfma_i32_16x16x64_i8(af[fm], bfc[fn], acc[fm][fn], 0, 0, 0);
    if (kt + 2 < 16) {  // refill the slot just consumed (2-deep cover)
#pragma unroll
      for (int fn = 0; fn < 4; ++fn)
        bfc[fn] = *(const i32x4*)(gBl + (kt + 2) * 64 + fn * 16384);
    }
  }

  __syncthreads();  // all Ap reads done: safe to overlay u.ep

  // ---- epilogue: acc elem j -> row fm*16+kg*4+j, col wn*64+fn*16+lr ----
  const float wsv_ = wS[0];
  f32x4 fa[4][4];
#pragma unroll
  for (int fm = 0; fm < 4; ++fm) {
    float sc[4];
#pragma unroll
    for (int j = 0; j < 4; ++j) sc[j] = rowSc[fm * 16 + kg * 4 + j] * wsv_;
#pragma unroll
    for (int fn = 0; fn < 4; ++fn) {
      const float bb = biasS[wn * 64 + fn * 16 + lr];
#pragma unroll
      for (int j = 0; j < 4; ++j)
        fa[fm][fn][j] = fmaxf((float)acc[fm][fn][j] * sc[j] + bb, 0.0f);
    }
  }
#pragma unroll
  for (int fm = 0; fm < 4; ++fm)
#pragma unroll
    for (int j = 0; j < 4; ++j) {
      float ss = 0.f, mx = 0.f;
#pragma unroll
      for (int fn = 0; fn < 4; ++fn) { float h = fa[fm][fn][j]; ss += h * h; mx = fmaxf(mx, h); }
#pragma unroll
      for (int m = 8; m >= 1; m >>= 1) { ss += __shfl_xor(ss, m); mx = fmaxf(mx, __shfl_xor(mx, m)); }
      if (lr == 0) {
        int rl = fm * 16 + kg * 4 + j;
        u.ep.sq[rl][wn] = ss;
        u.ep.mx[rl][wn] = mx;
      }
    }
  __syncthreads();
#pragma unroll
  for (int fm = 0; fm < 4; ++fm)
#pragma unroll
    for (int j = 0; j < 4; ++j) {
      const int rl = fm * 16 + kg * 4 + j;
      float sst = 0.f, mxt = 0.f;
#pragma unroll
      for (int w = 0; w < 8; ++w) {
        sst += u.ep.sq[rl][w];
        mxt = fmaxf(mxt, u.ep.mx[rl][w]);
      }
      float inv = 1.0f / sqrtf(sst * (1.0f / 512.0f) + 1e-6f);
      float amax = fmaxf(mxt * inv, 1e-5f);
      float s = 127.0f / amax;
      if (lr == 0 && wn == 0) rActOut[row0 + rl] = amax / 127.0f;
#pragma unroll
      for (int fn = 0; fn < 4; ++fn) {
        float xn = fa[fm][fn][j] * inv;
        int qi = (int)fminf(fmaxf(rintf(xn * s), -128.0f), 127.0f);
        XqOut[(row0 + rl) * 512 + wn * 64 + fn * 16 + lr] = (char)qi;
      }
    }
}

// ---------------- GEMM2 core (shared by sum-pass and write-pass) ----------------
// Computes acc for a 64x512 tile: A staged once (pre-swizzled source), 2-deep B-prefetch.
template <bool WRITE_PASS>
__global__ __launch_bounds__(512, 4) void kGemm2(
    const char* __restrict__ Xq, const char* __restrict__ Wq,
    const float* __restrict__ biasG, const float* __restrict__ rAct,
    const float* __restrict__ wS, const float* __restrict__ prior,
    float* __restrict__ outp, float* __restrict__ partG) {
  __shared__ __align__(16) char A[32768];  // [64][512] i8, col^((r&7)<<4)
  __shared__ float rowR[64];
  __shared__ float biasS[512];
  __shared__ float normS[512];

  const int tid = threadIdx.x;
  const int lane = tid & 63;
  const int wn = tid >> 6;
  const int lr = lane & 15;
  const int kg = lane >> 4;
  const size_t row0 = (size_t)blockIdx.x * 64;

  if (tid < 64) rowR[tid] = rAct[row0 + tid];
  biasS[tid] = biasG[tid];

  // stage whole 64x512 A-tile: linear LDS dest, XOR-swizzled global source
#pragma unroll
  for (int i = 0; i < 4; ++i) {
    const int r = i * 16 + wn * 2 + (lane >> 5);
    const int cs = ((lane & 31) * 16) ^ ((r & 7) << 4);
    GLOAD_LDS16(Xq + (row0 + r) * 512 + cs, &A[i * 8192 + wn * 1024]);
  }

  if constexpr (WRITE_PASS) {  // per-block normalizer: kNorm1's exact order
    const int b = blockIdx.x >> 4;
    float ns = 0.f;
#pragma unroll
    for (int i = 0; i < 16; ++i) ns += partG[(size_t)(b * 16 + i) * 512 + tid];
    normS[tid] = fmaxf(ns, 1e-10f);
  }

  const char* gBl = Wq + (size_t)(wn * 64 + lr) * 512 + kg * 16;
  i32x4 bf0[4], bf1[4];
#pragma unroll
  for (int fn = 0; fn < 4; ++fn) {
    bf0[fn] = *(const i32x4*)(gBl + fn * 8192);
    bf1[fn] = *(const i32x4*)(gBl + 64 + fn * 8192);
  }

  i32x4 acc[4][4];
#pragma unroll
  for (int a = 0; a < 4; ++a)
#pragma unroll
    for (int b = 0; b < 4; ++b) acc[a][b] = (i32x4){0, 0, 0, 0};

  __syncthreads();  // A staged (implicit vmcnt(0) drain)

  const int aswz = (lr & 7) << 4;
#pragma unroll
  for (int kt = 0; kt < 8; ++kt) {
    i32x4(&bfc)[4] = (kt & 1) ? bf1 : bf0;
    const int acol = (kt * 64 + kg * 16) ^ aswz;
    i32x4 af[4];
#pragma unroll
    for (int fm = 0; fm < 4; ++fm)
      af[fm] = *(const i32x4*)&A[(fm * 16 + lr) * 512 + acol];
#pragma unroll
    for (int fn = 0; fn < 4; ++fn)
#pragma unroll
      for (int fm = 0; fm < 4; ++fm)
        acc[fm][fn] = __builtin_amdgcn_mfma_i32_16x16x64_i8(af[fm], bfc[fn], acc[fm][fn], 0, 0, 0);
    if (kt + 2 < 8) {
#pragma unroll
      for (int fn = 0; fn < 4; ++fn)
        bfc[fn] = *(const i32x4*)(gBl + (kt + 2) * 64 + fn * 8192);
    }
  }

  // ---- epilogue ----
  const float wsv_ = wS[0];
  if constexpr (!WRITE_PASS) {
    // sum-pass: colsums only (no un write)
    float colsum[4] = {0.f, 0.f, 0.f, 0.f};
#pragma unroll
    for (int fm = 0; fm < 4; ++fm) {
      float sc[4];
#pragma unroll
      for (int j = 0; j < 4; ++j) sc[j] = rowR[fm * 16 + kg * 4 + j] * wsv_;
#pragma unroll
      for (int fn = 0; fn < 4; ++fn) {
        const int col = wn * 64 + fn * 16 + lr;
        const float bb = biasS[col];
#pragma unroll
        for (int j = 0; j < 4; ++j) {
          const size_t rg = row0 + fm * 16 + kg * 4 + j;
          float v = (float)acc[fm][fn][j] * sc[j] + bb;
          float like = 1.0f / (1.0f + expf(-v));
          float un = prior[rg * 512 + col] * like;
          colsum[fn] += un;
        }
      }
    }
#pragma unroll
    for (int fn = 0; fn < 4; ++fn) {
      colsum[fn] += __shfl_xor(colsum[fn], 16);
      colsum[fn] += __shfl_xor(colsum[fn], 32);
    }
    if (lane < 16) {
#pragma unroll
      for (int fn = 0; fn < 4; ++fn) normS[wn * 64 + fn * 16 + lane] = colsum[fn];
    }
    __syncthreads();
    partG[(size_t)blockIdx.x * 512 + tid] = normS[tid];
  } else {
    // write-pass: out = prior * sigmoid(v) / norm  (identical un arithmetic)
#pragma unroll
    for (int fm = 0; fm < 4; ++fm) {
      float sc[4];
#pragma unroll
      for (int j = 0; j < 4; ++j) sc[j] = rowR[fm * 16 + kg * 4 + j] * wsv_;
#pragma unroll
      for (int fn = 0; fn < 4; ++fn) {
        const int col = wn * 64 + fn * 16 + lr;
        const float bb = biasS[col];
        const float nrm = normS[col];
#pragma unroll
        for (int j = 0; j < 4; ++j) {
          const size_t rg = row0 + fm * 16 + kg * 4 + j;
          float v = (float)acc[fm][fn][j] * sc[j] + bb;
          float like = 1.0f / (1.0f + expf(-v));
          float un = prior[rg * 512 + col] * like;
          outp[rg * 512 + col] = un / nrm;
        }
      }
    }
  }
}

// ---------------- launcher ----------------
extern "C" void kernel_launch(void* const* d_in, const int* in_sizes, int n_in,
                              void* d_out, int out_size, void* d_ws, size_t ws_size,
                              hipStream_t stream) {
  const float* evid  = (const float*)d_in[0];   // [32,1024,512]
  const float* prior = (const float*)d_in[1];   // [32,1024,512]
  const float* W1    = (const float*)d_in[2];   // [512,1024]
  const float* b1    = (const float*)d_in[3];   // [512]
  const float* W2    = (const float*)d_in[4];   // [512,512]
  const float* b2    = (const float*)d_in[5];   // [512]
  float* out = (float*)d_out;

  char* ws = (char*)d_ws;
  char*   X2q   = ws;                              // 16,777,216 B (i8 [32768][512])
  char*   W1q   = ws + 16777216;                   //    524,288 B
  char*   W2q   = ws + 17301504;                   //    262,144 B
  float*  r2    = (float*)(ws + 17563648);         //    131,072 B
  double* part  = (double*)(ws + 17694720);        //      4,096 B
  float*  wsv   = (float*)(ws + 17698816);         //        256 B
  float*  partG = (float*)(ws + 17699072);         //  1,048,576 B (total ~18.7 MB)

  kWabs<<<512, 256, 0, stream>>>(W1, W2, part);
  kWfin<<<2, 256, 0, stream>>>(part, wsv);
  kWq<<<3072, 256, 0, stream>>>(W1, W2, wsv, W1q, W2q);
  kFused1<<<512, 512, 0, stream>>>(prior, evid, W1q, b1, wsv + 0, X2q, r2);
  kGemm2<false><<<512, 512, 0, stream>>>(X2q, W2q, b2, r2, wsv + 1, prior, nullptr, partG);
  kGemm2<true><<<512, 512, 0, stream>>>(X2q, W2q, b2, r2, wsv + 1, prior, out, partG);
}

// Round 14
// 132.148 us; speedup vs baseline: 1.1684x; 1.1684x over previous
//
#include <hip/hip_runtime.h>
#include <math.h>

typedef __attribute__((ext_vector_type(4))) int i32x4;
typedef __attribute__((ext_vector_type(2))) int i32x2;
typedef __attribute__((ext_vector_type(4))) float f32x4;

#define GLOAD_LDS16(g, l)                                          \
  __builtin_amdgcn_global_load_lds(                                \
      (const __attribute__((address_space(1))) void*)(g),          \
      (__attribute__((address_space(3))) void*)(l), 16, 0, 0)

// ---------------- weight quantization (merged: W1 blocks 0-255, W2 blocks 256-511) ----------
__global__ void kWabs(const float* __restrict__ w1, const float* __restrict__ w2,
                      double* __restrict__ part) {
  const bool second = blockIdx.x >= 256;
  const float* w = second ? w2 : w1;
  const int n = second ? 262144 : 524288;
  int t = (blockIdx.x & 255) * 256 + threadIdx.x;
  double s = 0.0;
  for (int i = t; i < n; i += 65536) s += (double)fabsf(w[i]);
#pragma unroll
  for (int m = 32; m >= 1; m >>= 1) s += __shfl_xor(s, m);
  __shared__ double sd[4];
  int lane = threadIdx.x & 63, wid = threadIdx.x >> 6;
  if (lane == 0) sd[wid] = s;
  __syncthreads();
  if (threadIdx.x == 0) part[blockIdx.x] = (sd[0] + sd[1]) + (sd[2] + sd[3]);
}

__global__ void kWfin(const double* __restrict__ part, float* __restrict__ wsv) {
  const double* p = part + blockIdx.x * 256;
  const double n = (blockIdx.x == 0) ? 524288.0 : 262144.0;
  double s = p[threadIdx.x];
#pragma unroll
  for (int m = 32; m >= 1; m >>= 1) s += __shfl_xor(s, m);
  __shared__ double sd[4];
  int lane = threadIdx.x & 63, wid = threadIdx.x >> 6;
  if (lane == 0) sd[wid] = s;
  __syncthreads();
  if (threadIdx.x == 0) {
    double tot = (sd[0] + sd[1]) + (sd[2] + sd[3]);
    wsv[blockIdx.x] = fmaxf((float)(tot / n), 1e-5f);  // = 1/scale_w
  }
}

__global__ void kWq(const float* __restrict__ w1, const float* __restrict__ w2,
                    const float* __restrict__ wsv,
                    char* __restrict__ wq1, char* __restrict__ wq2) {
  const bool second = blockIdx.x >= 2048;
  const float* w = second ? w2 : w1;
  char* wq = second ? wq2 : wq1;
  const float scale = 1.0f / wsv[second ? 1 : 0];
  int i = (second ? blockIdx.x - 2048 : blockIdx.x) * 256 + threadIdx.x;
  float q = fminf(fmaxf(rintf(w[i] * scale), -1.0f), 1.0f);
  wq[i] = (char)(int)q;
}

// ---------------- input RMSNorm + absmax quant: wave-per-row (round-5 best) ----------
__global__ __launch_bounds__(512) void kQ1(
    const float* __restrict__ prior, const float* __restrict__ evid,
    char* __restrict__ Xq, float* __restrict__ rAct) {
  const int w = threadIdx.x >> 6;
  const int l = threadIdx.x & 63;
  const size_t row = (size_t)blockIdx.x * 8 + w;
  const f32x4* pp = (const f32x4*)(prior + row * 512) + l * 2;
  const f32x4* pe = (const f32x4*)(evid + row * 512) + l * 2;
  f32x4 x[4];
  x[0] = pp[0]; x[1] = pp[1]; x[2] = pe[0]; x[3] = pe[1];
  float ss = 0.f, mx = 0.f;
#pragma unroll
  for (int v = 0; v < 4; ++v)
#pragma unroll
    for (int i = 0; i < 4; ++i) { float f = x[v][i]; ss += f * f; mx = fmaxf(mx, fabsf(f)); }
#pragma unroll
  for (int m = 32; m >= 1; m >>= 1) { ss += __shfl_xor(ss, m); mx = fmaxf(mx, __shfl_xor(mx, m)); }
  const float inv = 1.0f / sqrtf(ss * (1.0f / 1024.0f) + 1e-6f);
  const float amax = fmaxf(mx * inv, 1e-5f);
  const float s = 127.0f / amax;
  int pk[4];
#pragma unroll
  for (int v = 0; v < 4; ++v) {
    int p = 0;
#pragma unroll
    for (int i = 0; i < 4; ++i) {
      int qi = (int)fminf(fmaxf(rintf(x[v][i] * inv * s), -128.0f), 127.0f);
      p |= (qi & 255) << (8 * i);
    }
    pk[v] = p;
  }
  char* dst = Xq + row * 1024 + l * 8;
  *(i32x2*)dst = (i32x2){pk[0], pk[1]};          // prior half
  *(i32x2*)(dst + 512) = (i32x2){pk[2], pk[3]};  // evid half
  if (l == 0) rAct[row] = amax / 127.0f;
}

// ---------------- fused BitLinear GEMM, i8 MFMA, 64x512 tile, COUNTED-VMCNT pipeline ----
// T4 port: per K-step, STAGE(next) stays IN FLIGHT across the barrier; the wait before
// barrier-1 is counted (leaves exactly the just-issued loads outstanding). Safe because
// each wave stages precisely the B-rows it reads (producer==consumer); A needs barrier-1.
// Barrier-2 (no drain) protects buf[cur] from next step's STAGE overwrite.
template <int KDIM, bool L1>
__global__ __launch_bounds__(512, 4) void kGemm(
    const char* __restrict__ Xq, const char* __restrict__ Wq,
    const float* __restrict__ biasG, const float* __restrict__ rAct,
    const float* __restrict__ wS,
    char* __restrict__ XqOut, float* __restrict__ rActOut,
    const float* __restrict__ prior, float* __restrict__ outUn,
    float* __restrict__ partG) {
  struct Stage { char A[4096]; char B[32768]; };
  __shared__ __align__(16) union {
    Stage st[2];                                     // 73,728 B double buffer
    struct { float sq[64][8]; float mx[64][8]; } ep; // L1 epilogue overlay
  } u;
  __shared__ float rowR[64];
  __shared__ float biasS[512];
  __shared__ float normPart[512];

  const int tid = threadIdx.x;
  const int lane = tid & 63;
  const int wn = tid >> 6;   // wave -> 64-col strip (0..7)
  const int lr = lane & 15;
  const int kg = lane >> 4;  // 0..3
  const size_t row0 = (size_t)blockIdx.x * 64;

  if (tid < 64) rowR[tid] = rAct[row0 + tid];
  biasS[tid] = biasG[tid];

  i32x4 acc[4][4];
#pragma unroll
  for (int a = 0; a < 4; ++a)
#pragma unroll
    for (int b = 0; b < 4; ++b) acc[a][b] = (i32x4){0, 0, 0, 0};

  const int lrow = lane >> 2;       // row within a 16-row chunk
  const int lkb = (lane & 3) * 16;  // 16B k-slice within a 64B row

  const char* gA = Xq + (row0 + (wn & 3) * 16 + lrow) * (size_t)KDIM + lkb;
  const char* gB[4];
#pragma unroll
  for (int r = 0; r < 4; ++r)
    gB[r] = Wq + ((wn * 4 + r) * 16 + lrow) * (size_t)KDIM + lkb;

#define STAGE(b, k0)                                                   \
  do {                                                                 \
    if (wn < 4) GLOAD_LDS16(gA + (k0), &u.st[b].A[(wn & 3) * 1024]);   \
    _Pragma("unroll")                                                  \
    for (int r = 0; r < 4; ++r)                                        \
      GLOAD_LDS16(gB[r] + (k0), &u.st[b].B[(wn * 4 + r) * 1024]);      \
  } while (0)

  constexpr int NT = KDIM / 64;
  STAGE(0, 0);
  asm volatile("s_waitcnt vmcnt(0)" ::: "memory");  // prologue: buf0 ready (drains setup too)
  __builtin_amdgcn_s_barrier();

#pragma unroll
  for (int kt = 0; kt < NT; ++kt) {
    const int cur = kt & 1;
    if (kt + 1 < NT) {
      STAGE(cur ^ 1, (kt + 1) * 64);  // issue next-buffer loads: stay in flight
      // counted wait: drain buf[cur]'s loads (issued last step), keep the new ones flying
      if (wn < 4) asm volatile("s_waitcnt vmcnt(5)" ::: "memory");
      else        asm volatile("s_waitcnt vmcnt(4)" ::: "memory");
    } else {
      asm volatile("s_waitcnt vmcnt(0)" ::: "memory");
    }
    __builtin_amdgcn_s_barrier();        // barrier-1: buf[cur] staged by ALL waves (A!)
    __builtin_amdgcn_sched_barrier(0);   // pin: no ds_read hoisted above the barrier
    i32x4 af[4];
#pragma unroll
    for (int fm = 0; fm < 4; ++fm)
      af[fm] = *(const i32x4*)&u.st[cur].A[(fm * 16 + lr) * 64 + kg * 16];
#pragma unroll
    for (int fn = 0; fn < 4; ++fn) {
      i32x4 bf = *(const i32x4*)&u.st[cur].B[(wn * 64 + fn * 16 + lr) * 64 + kg * 16];
#pragma unroll
      for (int fm = 0; fm < 4; ++fm)
        acc[fm][fn] = __builtin_amdgcn_mfma_i32_16x16x64_i8(af[fm], bf, acc[fm][fn], 0, 0, 0);
    }
    __builtin_amdgcn_sched_barrier(0);   // pin: ds_reads complete before barrier-2
    __builtin_amdgcn_s_barrier();        // barrier-2: buf[cur] free for next STAGE (no drain)
  }
#undef STAGE

  // ---- epilogue: acc element j -> row fm*16+kg*4+j, col wn*64+fn*16+lr
  const float wsv_ = wS[0];

  if constexpr (L1) {
    f32x4 fa[4][4];
#pragma unroll
    for (int fm = 0; fm < 4; ++fm) {
      float sc[4];
#pragma unroll
      for (int j = 0; j < 4; ++j) sc[j] = rowR[fm * 16 + kg * 4 + j] * wsv_;
#pragma unroll
      for (int fn = 0; fn < 4; ++fn) {
        const float bb = biasS[wn * 64 + fn * 16 + lr];
#pragma unroll
        for (int j = 0; j < 4; ++j)
          fa[fm][fn][j] = fmaxf((float)acc[fm][fn][j] * sc[j] + bb, 0.0f);
      }
    }
#pragma unroll
    for (int fm = 0; fm < 4; ++fm)
#pragma unroll
      for (int j = 0; j < 4; ++j) {
        float ss = 0.f, mx = 0.f;
#pragma unroll
        for (int fn = 0; fn < 4; ++fn) { float h = fa[fm][fn][j]; ss += h * h; mx = fmaxf(mx, h); }
#pragma unroll
        for (int m = 8; m >= 1; m >>= 1) { ss += __shfl_xor(ss, m); mx = fmaxf(mx, __shfl_xor(mx, m)); }
        if (lr == 0) {
          int rl = fm * 16 + kg * 4 + j;
          u.ep.sq[rl][wn] = ss;
          u.ep.mx[rl][wn] = mx;
        }
      }
    __syncthreads();
#pragma unroll
    for (int fm = 0; fm < 4; ++fm)
#pragma unroll
      for (int j = 0; j < 4; ++j) {
        const int rl = fm * 16 + kg * 4 + j;
        float sst = 0.f, mxt = 0.f;
#pragma unroll
        for (int w = 0; w < 8; ++w) {
          sst += u.ep.sq[rl][w];
          mxt = fmaxf(mxt, u.ep.mx[rl][w]);
        }
        float inv = 1.0f / sqrtf(sst * (1.0f / 512.0f) + 1e-6f);
        float amax = fmaxf(mxt * inv, 1e-5f);
        float s = 127.0f / amax;
        if (lr == 0 && wn == 0) rActOut[row0 + rl] = amax / 127.0f;
#pragma unroll
        for (int fn = 0; fn < 4; ++fn) {
          float xn = fa[fm][fn][j] * inv;
          int qi = (int)fminf(fmaxf(rintf(xn * s), -128.0f), 127.0f);
          XqOut[(row0 + rl) * 512 + wn * 64 + fn * 16 + lr] = (char)qi;
        }
      }
  } else {
    float colsum[4] = {0.f, 0.f, 0.f, 0.f};
#pragma unroll
    for (int fm = 0; fm < 4; ++fm) {
      float sc[4];
#pragma unroll
      for (int j = 0; j < 4; ++j) sc[j] = rowR[fm * 16 + kg * 4 + j] * wsv_;
#pragma unroll
      for (int fn = 0; fn < 4; ++fn) {
        const int col = wn * 64 + fn * 16 + lr;
        const float bb = biasS[col];
#pragma unroll
        for (int j = 0; j < 4; ++j) {
          const size_t rg = row0 + fm * 16 + kg * 4 + j;
          float v = (float)acc[fm][fn][j] * sc[j] + bb;
          float like = 1.0f / (1.0f + expf(-v));
          float un = prior[rg * 512 + col] * like;
          outUn[rg * 512 + col] = un;
          colsum[fn] += un;
        }
      }
    }
#pragma unroll
    for (int fn = 0; fn < 4; ++fn) {
      colsum[fn] += __shfl_xor(colsum[fn], 16);
      colsum[fn] += __shfl_xor(colsum[fn], 32);
    }
    if (lane < 16) {
#pragma unroll
      for (int fn = 0; fn < 4; ++fn) normPart[wn * 64 + fn * 16 + lane] = colsum[fn];
    }
    __syncthreads();
    partG[(size_t)blockIdx.x * 512 + tid] = normPart[tid];
  }
}

// ---------------- normalization over S ----------------
__global__ void kNorm1(const float* __restrict__ partG, float* __restrict__ normA) {
  const int b = blockIdx.x, f = threadIdx.x;
  float s = 0.f;
#pragma unroll
  for (int i = 0; i < 16; ++i) s += partG[(size_t)(b * 16 + i) * 512 + f];
  normA[b * 512 + f] = fmaxf(s, 1e-10f);
}

__global__ void kNorm2(float* __restrict__ out, const float* __restrict__ normA) {
  const size_t i4 = (size_t)blockIdx.x * blockDim.x + threadIdx.x;
  f32x4 v = ((const f32x4*)out)[i4];
  const int f4 = (int)(i4 & 127);
  const int b = (int)(i4 >> 17);
  f32x4 n = ((const f32x4*)normA)[b * 128 + f4];
  v[0] /= n[0]; v[1] /= n[1]; v[2] /= n[2]; v[3] /= n[3];
  ((f32x4*)out)[i4] = v;
}

// ---------------- launcher ----------------
extern "C" void kernel_launch(void* const* d_in, const int* in_sizes, int n_in,
                              void* d_out, int out_size, void* d_ws, size_t ws_size,
                              hipStream_t stream) {
  const float* evid  = (const float*)d_in[0];   // [32,1024,512]
  const float* prior = (const float*)d_in[1];   // [32,1024,512]
  const float* W1    = (const float*)d_in[2];   // [512,1024]
  const float* b1    = (const float*)d_in[3];   // [512]
  const float* W2    = (const float*)d_in[4];   // [512,512]
  const float* b2    = (const float*)d_in[5];   // [512]
  float* out = (float*)d_out;

  char* ws = (char*)d_ws;
  char*   X2q   = ws;                              // 16,777,216 B (i8 [32768][512])
  char*   W1q   = ws + 16777216;                   //    524,288 B
  char*   W2q   = ws + 17301504;                   //    262,144 B
  float*  r1    = (float*)(ws + 17563648);         //    131,072 B
  float*  r2    = (float*)(ws + 17694720);         //    131,072 B
  double* part  = (double*)(ws + 17825792);        //      4,096 B
  float*  wsv   = (float*)(ws + 17829888);         //        256 B
  float*  partG = (float*)(ws + 17830144);         //  1,048,576 B
  float*  normA = (float*)(ws + 18878720);         //     65,536 B (total ~18.9 MB)

  // X1q (i8 [32768][1024] = 33.5 MB) lives in d_out (67 MB); dead before GEMM2 writes.
  char* X1q = (char*)d_out;

  kWabs<<<512, 256, 0, stream>>>(W1, W2, part);
  kWfin<<<2, 256, 0, stream>>>(part, wsv);
  kWq<<<3072, 256, 0, stream>>>(W1, W2, wsv, W1q, W2q);
  kQ1<<<4096, 512, 0, stream>>>(prior, evid, X1q, r1);
  kGemm<1024, true><<<512, 512, 0, stream>>>(X1q, W1q, b1, r1, wsv + 0,
                                             X2q, r2, nullptr, nullptr, nullptr);
  kGemm<512, false><<<512, 512, 0, stream>>>(X2q, W2q, b2, r2, wsv + 1,
                                             nullptr, nullptr, prior, out, partG);
  kNorm1<<<32, 512, 0, stream>>>(partG, normA);
  kNorm2<<<16384, 256, 0, stream>>>(out, normA);
}

// Round 15
// 127.015 us; speedup vs baseline: 1.2156x; 1.0404x over previous
//
#include <hip/hip_runtime.h>
#include <math.h>

typedef __attribute__((ext_vector_type(4))) int i32x4;
typedef __attribute__((ext_vector_type(2))) int i32x2;
typedef __attribute__((ext_vector_type(4))) float f32x4;

#define GLOAD_LDS16(g, l)                                          \
  __builtin_amdgcn_global_load_lds(                                \
      (const __attribute__((address_space(1))) void*)(g),          \
      (__attribute__((address_space(3))) void*)(l), 16, 0, 0)

static __device__ __forceinline__ unsigned short f2bf(float f) {
  union { float f; unsigned u; } c; c.f = f;
  unsigned u = c.u;
  return (unsigned short)((u + 0x7fffu + ((u >> 16) & 1u)) >> 16);  // RNE
}

// ---------------- weight quantization (merged: W1 blocks 0-255, W2 blocks 256-511) ----------
__global__ void kWabs(const float* __restrict__ w1, const float* __restrict__ w2,
                      double* __restrict__ part) {
  const bool second = blockIdx.x >= 256;
  const float* w = second ? w2 : w1;
  const int n = second ? 262144 : 524288;
  int t = (blockIdx.x & 255) * 256 + threadIdx.x;
  double s = 0.0;
  for (int i = t; i < n; i += 65536) s += (double)fabsf(w[i]);
#pragma unroll
  for (int m = 32; m >= 1; m >>= 1) s += __shfl_xor(s, m);
  __shared__ double sd[4];
  int lane = threadIdx.x & 63, wid = threadIdx.x >> 6;
  if (lane == 0) sd[wid] = s;
  __syncthreads();
  if (threadIdx.x == 0) part[blockIdx.x] = (sd[0] + sd[1]) + (sd[2] + sd[3]);
}

__global__ void kWfin(const double* __restrict__ part, float* __restrict__ wsv) {
  const double* p = part + blockIdx.x * 256;
  const double n = (blockIdx.x == 0) ? 524288.0 : 262144.0;
  double s = p[threadIdx.x];
#pragma unroll
  for (int m = 32; m >= 1; m >>= 1) s += __shfl_xor(s, m);
  __shared__ double sd[4];
  int lane = threadIdx.x & 63, wid = threadIdx.x >> 6;
  if (lane == 0) sd[wid] = s;
  __syncthreads();
  if (threadIdx.x == 0) {
    double tot = (sd[0] + sd[1]) + (sd[2] + sd[3]);
    wsv[blockIdx.x] = fmaxf((float)(tot / n), 1e-5f);  // = 1/scale_w
  }
}

__global__ void kWq(const float* __restrict__ w1, const float* __restrict__ w2,
                    const float* __restrict__ wsv,
                    char* __restrict__ wq1, char* __restrict__ wq2) {
  const bool second = blockIdx.x >= 2048;
  const float* w = second ? w2 : w1;
  char* wq = second ? wq2 : wq1;
  const float scale = 1.0f / wsv[second ? 1 : 0];
  int i = (second ? blockIdx.x - 2048 : blockIdx.x) * 256 + threadIdx.x;
  float q = fminf(fmaxf(rintf(w[i] * scale), -1.0f), 1.0f);
  wq[i] = (char)(int)q;
}

// ---------------- input RMSNorm + absmax quant: wave-per-row ----------
__global__ __launch_bounds__(512) void kQ1(
    const float* __restrict__ prior, const float* __restrict__ evid,
    char* __restrict__ Xq, float* __restrict__ rAct) {
  const int w = threadIdx.x >> 6;
  const int l = threadIdx.x & 63;
  const size_t row = (size_t)blockIdx.x * 8 + w;
  const f32x4* pp = (const f32x4*)(prior + row * 512) + l * 2;
  const f32x4* pe = (const f32x4*)(evid + row * 512) + l * 2;
  f32x4 x[4];
  x[0] = pp[0]; x[1] = pp[1]; x[2] = pe[0]; x[3] = pe[1];
  float ss = 0.f, mx = 0.f;
#pragma unroll
  for (int v = 0; v < 4; ++v)
#pragma unroll
    for (int i = 0; i < 4; ++i) { float f = x[v][i]; ss += f * f; mx = fmaxf(mx, fabsf(f)); }
#pragma unroll
  for (int m = 32; m >= 1; m >>= 1) { ss += __shfl_xor(ss, m); mx = fmaxf(mx, __shfl_xor(mx, m)); }
  const float inv = 1.0f / sqrtf(ss * (1.0f / 1024.0f) + 1e-6f);
  const float amax = fmaxf(mx * inv, 1e-5f);
  const float s = 127.0f / amax;
  int pk[4];
#pragma unroll
  for (int v = 0; v < 4; ++v) {
    int p = 0;
#pragma unroll
    for (int i = 0; i < 4; ++i) {
      int qi = (int)fminf(fmaxf(rintf(x[v][i] * inv * s), -128.0f), 127.0f);
      p |= (qi & 255) << (8 * i);
    }
    pk[v] = p;
  }
  char* dst = Xq + row * 1024 + l * 8;
  *(i32x2*)dst = (i32x2){pk[0], pk[1]};          // prior half
  *(i32x2*)(dst + 512) = (i32x2){pk[2], pk[3]};  // evid half
  if (l == 0) rAct[row] = amax / 127.0f;
}

// ---------------- fused BitLinear GEMM, i8 MFMA, 64x512 tile, counted-vmcnt pipeline ----
// L2 epilogue: BF=true -> write un as bf16 to unBf (colsum still from f32 un);
//              BF=false -> write un f32 to outUn (round-14 path).
template <int KDIM, bool L1, bool BF>
__global__ __launch_bounds__(512, 4) void kGemm(
    const char* __restrict__ Xq, const char* __restrict__ Wq,
    const float* __restrict__ biasG, const float* __restrict__ rAct,
    const float* __restrict__ wS,
    char* __restrict__ XqOut, float* __restrict__ rActOut,
    const float* __restrict__ prior, float* __restrict__ outUn,
    unsigned short* __restrict__ unBf, float* __restrict__ partG) {
  struct Stage { char A[4096]; char B[32768]; };
  __shared__ __align__(16) union {
    Stage st[2];                                     // 73,728 B double buffer
    struct { float sq[64][8]; float mx[64][8]; } ep; // L1 epilogue overlay
  } u;
  __shared__ float rowR[64];
  __shared__ float biasS[512];
  __shared__ float normPart[512];

  const int tid = threadIdx.x;
  const int lane = tid & 63;
  const int wn = tid >> 6;   // wave -> 64-col strip (0..7)
  const int lr = lane & 15;
  const int kg = lane >> 4;  // 0..3
  const size_t row0 = (size_t)blockIdx.x * 64;

  if (tid < 64) rowR[tid] = rAct[row0 + tid];
  biasS[tid] = biasG[tid];

  i32x4 acc[4][4];
#pragma unroll
  for (int a = 0; a < 4; ++a)
#pragma unroll
    for (int b = 0; b < 4; ++b) acc[a][b] = (i32x4){0, 0, 0, 0};

  const int lrow = lane >> 2;       // row within a 16-row chunk
  const int lkb = (lane & 3) * 16;  // 16B k-slice within a 64B row

  const char* gA = Xq + (row0 + (wn & 3) * 16 + lrow) * (size_t)KDIM + lkb;
  const char* gB[4];
#pragma unroll
  for (int r = 0; r < 4; ++r)
    gB[r] = Wq + ((wn * 4 + r) * 16 + lrow) * (size_t)KDIM + lkb;

#define STAGE(b, k0)                                                   \
  do {                                                                 \
    if (wn < 4) GLOAD_LDS16(gA + (k0), &u.st[b].A[(wn & 3) * 1024]);   \
    _Pragma("unroll")                                                  \
    for (int r = 0; r < 4; ++r)                                        \
      GLOAD_LDS16(gB[r] + (k0), &u.st[b].B[(wn * 4 + r) * 1024]);      \
  } while (0)

  constexpr int NT = KDIM / 64;
  STAGE(0, 0);
  asm volatile("s_waitcnt vmcnt(0)" ::: "memory");
  __builtin_amdgcn_s_barrier();

#pragma unroll
  for (int kt = 0; kt < NT; ++kt) {
    const int cur = kt & 1;
    if (kt + 1 < NT) {
      STAGE(cur ^ 1, (kt + 1) * 64);  // next-buffer loads stay in flight across barrier
      if (wn < 4) asm volatile("s_waitcnt vmcnt(5)" ::: "memory");
      else        asm volatile("s_waitcnt vmcnt(4)" ::: "memory");
    } else {
      asm volatile("s_waitcnt vmcnt(0)" ::: "memory");
    }
    __builtin_amdgcn_s_barrier();        // buf[cur] staged by ALL waves
    __builtin_amdgcn_sched_barrier(0);
    i32x4 af[4];
#pragma unroll
    for (int fm = 0; fm < 4; ++fm)
      af[fm] = *(const i32x4*)&u.st[cur].A[(fm * 16 + lr) * 64 + kg * 16];
#pragma unroll
    for (int fn = 0; fn < 4; ++fn) {
      i32x4 bf = *(const i32x4*)&u.st[cur].B[(wn * 64 + fn * 16 + lr) * 64 + kg * 16];
#pragma unroll
      for (int fm = 0; fm < 4; ++fm)
        acc[fm][fn] = __builtin_amdgcn_mfma_i32_16x16x64_i8(af[fm], bf, acc[fm][fn], 0, 0, 0);
    }
    __builtin_amdgcn_sched_barrier(0);
    __builtin_amdgcn_s_barrier();        // buf[cur] free for next STAGE (no drain)
  }
#undef STAGE

  // ---- epilogue: acc element j -> row fm*16+kg*4+j, col wn*64+fn*16+lr
  const float wsv_ = wS[0];

  if constexpr (L1) {
    f32x4 fa[4][4];
#pragma unroll
    for (int fm = 0; fm < 4; ++fm) {
      float sc[4];
#pragma unroll
      for (int j = 0; j < 4; ++j) sc[j] = rowR[fm * 16 + kg * 4 + j] * wsv_;
#pragma unroll
      for (int fn = 0; fn < 4; ++fn) {
        const float bb = biasS[wn * 64 + fn * 16 + lr];
#pragma unroll
        for (int j = 0; j < 4; ++j)
          fa[fm][fn][j] = fmaxf((float)acc[fm][fn][j] * sc[j] + bb, 0.0f);
      }
    }
#pragma unroll
    for (int fm = 0; fm < 4; ++fm)
#pragma unroll
      for (int j = 0; j < 4; ++j) {
        float ss = 0.f, mx = 0.f;
#pragma unroll
        for (int fn = 0; fn < 4; ++fn) { float h = fa[fm][fn][j]; ss += h * h; mx = fmaxf(mx, h); }
#pragma unroll
        for (int m = 8; m >= 1; m >>= 1) { ss += __shfl_xor(ss, m); mx = fmaxf(mx, __shfl_xor(mx, m)); }
        if (lr == 0) {
          int rl = fm * 16 + kg * 4 + j;
          u.ep.sq[rl][wn] = ss;
          u.ep.mx[rl][wn] = mx;
        }
      }
    __syncthreads();
#pragma unroll
    for (int fm = 0; fm < 4; ++fm)
#pragma unroll
      for (int j = 0; j < 4; ++j) {
        const int rl = fm * 16 + kg * 4 + j;
        float sst = 0.f, mxt = 0.f;
#pragma unroll
        for (int w = 0; w < 8; ++w) {
          sst += u.ep.sq[rl][w];
          mxt = fmaxf(mxt, u.ep.mx[rl][w]);
        }
        float inv = 1.0f / sqrtf(sst * (1.0f / 512.0f) + 1e-6f);
        float amax = fmaxf(mxt * inv, 1e-5f);
        float s = 127.0f / amax;
        if (lr == 0 && wn == 0) rActOut[row0 + rl] = amax / 127.0f;
#pragma unroll
        for (int fn = 0; fn < 4; ++fn) {
          float xn = fa[fm][fn][j] * inv;
          int qi = (int)fminf(fmaxf(rintf(xn * s), -128.0f), 127.0f);
          XqOut[(row0 + rl) * 512 + wn * 64 + fn * 16 + lr] = (char)qi;
        }
      }
  } else {
    float colsum[4] = {0.f, 0.f, 0.f, 0.f};
#pragma unroll
    for (int fm = 0; fm < 4; ++fm) {
      float sc[4];
#pragma unroll
      for (int j = 0; j < 4; ++j) sc[j] = rowR[fm * 16 + kg * 4 + j] * wsv_;
#pragma unroll
      for (int fn = 0; fn < 4; ++fn) {
        const int col = wn * 64 + fn * 16 + lr;
        const float bb = biasS[col];
#pragma unroll
        for (int j = 0; j < 4; ++j) {
          const size_t rg = row0 + fm * 16 + kg * 4 + j;
          float v = (float)acc[fm][fn][j] * sc[j] + bb;
          float like = 1.0f / (1.0f + expf(-v));
          float un = prior[rg * 512 + col] * like;   // exact f32 for the normalizer
          if constexpr (BF) unBf[rg * 512 + col] = f2bf(un);
          else              outUn[rg * 512 + col] = un;
          colsum[fn] += un;
        }
      }
    }
#pragma unroll
    for (int fn = 0; fn < 4; ++fn) {
      colsum[fn] += __shfl_xor(colsum[fn], 16);
      colsum[fn] += __shfl_xor(colsum[fn], 32);
    }
    if (lane < 16) {
#pragma unroll
      for (int fn = 0; fn < 4; ++fn) normPart[wn * 64 + fn * 16 + lane] = colsum[fn];
    }
    __syncthreads();
    partG[(size_t)blockIdx.x * 512 + tid] = normPart[tid];
  }
}

// ---------------- normalization over S ----------------
__global__ void kNorm1(const float* __restrict__ partG, float* __restrict__ normA) {
  const int b = blockIdx.x, f = threadIdx.x;
  float s = 0.f;
#pragma unroll
  for (int i = 0; i < 16; ++i) s += partG[(size_t)(b * 16 + i) * 512 + f];
  normA[b * 512 + f] = fmaxf(s, 1e-10f);
}

// f32 in-place path (round-14)
__global__ void kNorm2(float* __restrict__ out, const float* __restrict__ normA) {
  const size_t i4 = (size_t)blockIdx.x * blockDim.x + threadIdx.x;
  f32x4 v = ((const f32x4*)out)[i4];
  const int f4 = (int)(i4 & 127);
  const int b = (int)(i4 >> 17);
  f32x4 n = ((const f32x4*)normA)[b * 128 + f4];
  v[0] /= n[0]; v[1] /= n[1]; v[2] /= n[2]; v[3] /= n[3];
  ((f32x4*)out)[i4] = v;
}

// bf16-un path: read 8 bf16 (16B), divide by normA, write 8 f32 (32B)
__global__ void kNorm2bf(const unsigned short* __restrict__ unBf,
                         float* __restrict__ out, const float* __restrict__ normA) {
  const size_t t = (size_t)blockIdx.x * blockDim.x + threadIdx.x;  // 8-elem group index
  const size_t e0 = t * 8;
  i32x4 raw = *(const i32x4*)(unBf + e0);
  const int b = (int)(e0 >> 19);          // 512*1024 elems per batch
  const int f0 = (int)(e0 & 511);
  f32x4 n0 = *(const f32x4*)(normA + b * 512 + f0);
  f32x4 n1 = *(const f32x4*)(normA + b * 512 + f0 + 4);
  f32x4 o0, o1;
#pragma unroll
  for (int k = 0; k < 4; ++k) {
    unsigned w = (unsigned)raw[k];
    union { unsigned u; float f; } lo, hi;
    lo.u = (w & 0xffffu) << 16;
    hi.u = (w & 0xffff0000u);
    if (k < 2) { o0[k * 2] = lo.f; o0[k * 2 + 1] = hi.f; }
    else       { o1[(k - 2) * 2] = lo.f; o1[(k - 2) * 2 + 1] = hi.f; }
  }
  o0[0] /= n0[0]; o0[1] /= n0[1]; o0[2] /= n0[2]; o0[3] /= n0[3];
  o1[0] /= n1[0]; o1[1] /= n1[1]; o1[2] /= n1[2]; o1[3] /= n1[3];
  *(f32x4*)(out + e0) = o0;
  *(f32x4*)(out + e0 + 4) = o1;
}

// ---------------- launcher ----------------
extern "C" void kernel_launch(void* const* d_in, const int* in_sizes, int n_in,
                              void* d_out, int out_size, void* d_ws, size_t ws_size,
                              hipStream_t stream) {
  const float* evid  = (const float*)d_in[0];   // [32,1024,512]
  const float* prior = (const float*)d_in[1];   // [32,1024,512]
  const float* W1    = (const float*)d_in[2];   // [512,1024]
  const float* b1    = (const float*)d_in[3];   // [512]
  const float* W2    = (const float*)d_in[4];   // [512,512]
  const float* b2    = (const float*)d_in[5];   // [512]
  float* out = (float*)d_out;

  char* ws = (char*)d_ws;
  char*   X2q   = ws;                              // 16,777,216 B (i8 [32768][512])
  char*   W1q   = ws + 16777216;                   //    524,288 B
  char*   W2q   = ws + 17301504;                   //    262,144 B
  float*  r1    = (float*)(ws + 17563648);         //    131,072 B
  float*  r2    = (float*)(ws + 17694720);         //    131,072 B
  double* part  = (double*)(ws + 17825792);        //      4,096 B
  float*  wsv   = (float*)(ws + 17829888);         //        256 B
  float*  partG = (float*)(ws + 17830144);         //  1,048,576 B
  float*  normA = (float*)(ws + 18878720);         //     65,536 B   -> 18,944,256 B
  unsigned short* unBf = (unsigned short*)(ws + 18944256);  // 33,554,432 B (optional)
  const bool useBf = ws_size >= (size_t)18944256 + 33554432;

  // X1q (i8 [32768][1024] = 33.5 MB) lives in d_out (67 MB); dead before un/out writes.
  char* X1q = (char*)d_out;

  kWabs<<<512, 256, 0, stream>>>(W1, W2, part);
  kWfin<<<2, 256, 0, stream>>>(part, wsv);
  kWq<<<3072, 256, 0, stream>>>(W1, W2, wsv, W1q, W2q);
  kQ1<<<4096, 512, 0, stream>>>(prior, evid, X1q, r1);
  kGemm<1024, true, false><<<512, 512, 0, stream>>>(X1q, W1q, b1, r1, wsv + 0,
                                                    X2q, r2, nullptr, nullptr, nullptr, nullptr);
  if (useBf) {
    kGemm<512, false, true><<<512, 512, 0, stream>>>(X2q, W2q, b2, r2, wsv + 1,
                                                     nullptr, nullptr, prior, nullptr, unBf, partG);
    kNorm1<<<32, 512, 0, stream>>>(partG, normA);
    kNorm2bf<<<8192, 256, 0, stream>>>(unBf, out, normA);
  } else {
    kGemm<512, false, false><<<512, 512, 0, stream>>>(X2q, W2q, b2, r2, wsv + 1,
                                                      nullptr, nullptr, prior, out, nullptr, partG);
    kNorm1<<<32, 512, 0, stream>>>(partG, normA);
    kNorm2<<<16384, 256, 0, stream>>>(out, normA);
  }
}

// Round 16
// 126.981 us; speedup vs baseline: 1.2160x; 1.0003x over previous
//
#include <hip/hip_runtime.h>
#include <math.h>

typedef __attribute__((ext_vector_type(4))) int i32x4;
typedef __attribute__((ext_vector_type(2))) int i32x2;
typedef __attribute__((ext_vector_type(4))) float f32x4;

#define GLOAD_LDS16(g, l)                                          \
  __builtin_amdgcn_global_load_lds(                                \
      (const __attribute__((address_space(1))) void*)(g),          \
      (__attribute__((address_space(3))) void*)(l), 16, 0, 0)

static __device__ __forceinline__ unsigned short f2bf(float f) {
  union { float f; unsigned u; } c; c.f = f;
  unsigned u = c.u;
  return (unsigned short)((u + 0x7fffu + ((u >> 16) & 1u)) >> 16);  // RNE
}

// ---------------- weight quantization (merged: W1 blocks 0-255, W2 blocks 256-511) ----------
__global__ void kWabs(const float* __restrict__ w1, const float* __restrict__ w2,
                      double* __restrict__ part) {
  const bool second = blockIdx.x >= 256;
  const float* w = second ? w2 : w1;
  const int n = second ? 262144 : 524288;
  int t = (blockIdx.x & 255) * 256 + threadIdx.x;
  double s = 0.0;
  for (int i = t; i < n; i += 65536) s += (double)fabsf(w[i]);
#pragma unroll
  for (int m = 32; m >= 1; m >>= 1) s += __shfl_xor(s, m);
  __shared__ double sd[4];
  int lane = threadIdx.x & 63, wid = threadIdx.x >> 6;
  if (lane == 0) sd[wid] = s;
  __syncthreads();
  if (threadIdx.x == 0) part[blockIdx.x] = (sd[0] + sd[1]) + (sd[2] + sd[3]);
}

__global__ void kWfin(const double* __restrict__ part, float* __restrict__ wsv) {
  const double* p = part + blockIdx.x * 256;
  const double n = (blockIdx.x == 0) ? 524288.0 : 262144.0;
  double s = p[threadIdx.x];
#pragma unroll
  for (int m = 32; m >= 1; m >>= 1) s += __shfl_xor(s, m);
  __shared__ double sd[4];
  int lane = threadIdx.x & 63, wid = threadIdx.x >> 6;
  if (lane == 0) sd[wid] = s;
  __syncthreads();
  if (threadIdx.x == 0) {
    double tot = (sd[0] + sd[1]) + (sd[2] + sd[3]);
    wsv[blockIdx.x] = fmaxf((float)(tot / n), 1e-5f);  // = 1/scale_w
  }
}

__global__ void kWq(const float* __restrict__ w1, const float* __restrict__ w2,
                    const float* __restrict__ wsv,
                    char* __restrict__ wq1, char* __restrict__ wq2) {
  const bool second = blockIdx.x >= 2048;
  const float* w = second ? w2 : w1;
  char* wq = second ? wq2 : wq1;
  const float scale = 1.0f / wsv[second ? 1 : 0];
  int i = (second ? blockIdx.x - 2048 : blockIdx.x) * 256 + threadIdx.x;
  float q = fminf(fmaxf(rintf(w[i] * scale), -1.0f), 1.0f);
  wq[i] = (char)(int)q;
}

// ---------------- input RMSNorm + absmax quant: wave-per-row, 16B-contiguous lanes ------
// Lane l loads quarter v at src4[v*64 + l]: each load instruction = 64 lanes x contiguous
// 16B = one fully-utilized 1KB segment (was 32B-stride = 2KB span, lines half-used).
__global__ __launch_bounds__(512) void kQ1(
    const float* __restrict__ prior, const float* __restrict__ evid,
    char* __restrict__ Xq, float* __restrict__ rAct) {
  const int w = threadIdx.x >> 6;
  const int l = threadIdx.x & 63;
  const size_t row = (size_t)blockIdx.x * 8 + w;
  const f32x4* pp = (const f32x4*)(prior + row * 512);
  const f32x4* pe = (const f32x4*)(evid + row * 512);
  f32x4 x[4];
  x[0] = pp[l];       // prior floats [4l .. 4l+3]
  x[1] = pp[64 + l];  // prior floats [256+4l ..]
  x[2] = pe[l];       // evid  floats [4l ..]
  x[3] = pe[64 + l];  // evid  floats [256+4l ..]
  float ss = 0.f, mx = 0.f;
#pragma unroll
  for (int v = 0; v < 4; ++v)
#pragma unroll
    for (int i = 0; i < 4; ++i) { float f = x[v][i]; ss += f * f; mx = fmaxf(mx, fabsf(f)); }
#pragma unroll
  for (int m = 32; m >= 1; m >>= 1) { ss += __shfl_xor(ss, m); mx = fmaxf(mx, __shfl_xor(mx, m)); }
  const float inv = 1.0f / sqrtf(ss * (1.0f / 1024.0f) + 1e-6f);
  const float amax = fmaxf(mx * inv, 1e-5f);
  const float s = 127.0f / amax;
  int pk[4];
#pragma unroll
  for (int v = 0; v < 4; ++v) {
    int p = 0;
#pragma unroll
    for (int i = 0; i < 4; ++i) {
      int qi = (int)fminf(fmaxf(rintf(x[v][i] * inv * s), -128.0f), 127.0f);
      p |= (qi & 255) << (8 * i);
    }
    pk[v] = p;
  }
  // X1q[row][b]: b<512 = prior float b; b>=512 = evid float b-512 (same layout as before)
  char* dst = Xq + row * 1024;
  *(int*)(dst + 4 * l)       = pk[0];
  *(int*)(dst + 256 + 4 * l) = pk[1];
  *(int*)(dst + 512 + 4 * l) = pk[2];
  *(int*)(dst + 768 + 4 * l) = pk[3];
  if (l == 0) rAct[row] = amax / 127.0f;
}

// ---------------- fused BitLinear GEMM, i8 MFMA, 64x512 tile, counted-vmcnt pipeline ----
template <int KDIM, bool L1, bool BF>
__global__ __launch_bounds__(512, 4) void kGemm(
    const char* __restrict__ Xq, const char* __restrict__ Wq,
    const float* __restrict__ biasG, const float* __restrict__ rAct,
    const float* __restrict__ wS,
    char* __restrict__ XqOut, float* __restrict__ rActOut,
    const float* __restrict__ prior, float* __restrict__ outUn,
    unsigned short* __restrict__ unBf, float* __restrict__ partG) {
  struct Stage { char A[4096]; char B[32768]; };
  __shared__ __align__(16) union {
    Stage st[2];                                     // 73,728 B double buffer
    struct { float sq[64][8]; float mx[64][8]; } ep; // L1 epilogue overlay
  } u;
  __shared__ float rowR[64];
  __shared__ float biasS[512];
  __shared__ float normPart[512];

  const int tid = threadIdx.x;
  const int lane = tid & 63;
  const int wn = tid >> 6;   // wave -> 64-col strip (0..7)
  const int lr = lane & 15;
  const int kg = lane >> 4;  // 0..3
  const size_t row0 = (size_t)blockIdx.x * 64;

  if (tid < 64) rowR[tid] = rAct[row0 + tid];
  biasS[tid] = biasG[tid];

  i32x4 acc[4][4];
#pragma unroll
  for (int a = 0; a < 4; ++a)
#pragma unroll
    for (int b = 0; b < 4; ++b) acc[a][b] = (i32x4){0, 0, 0, 0};

  const int lrow = lane >> 2;       // row within a 16-row chunk
  const int lkb = (lane & 3) * 16;  // 16B k-slice within a 64B row

  const char* gA = Xq + (row0 + (wn & 3) * 16 + lrow) * (size_t)KDIM + lkb;
  const char* gB[4];
#pragma unroll
  for (int r = 0; r < 4; ++r)
    gB[r] = Wq + ((wn * 4 + r) * 16 + lrow) * (size_t)KDIM + lkb;

#define STAGE(b, k0)                                                   \
  do {                                                                 \
    if (wn < 4) GLOAD_LDS16(gA + (k0), &u.st[b].A[(wn & 3) * 1024]);   \
    _Pragma("unroll")                                                  \
    for (int r = 0; r < 4; ++r)                                        \
      GLOAD_LDS16(gB[r] + (k0), &u.st[b].B[(wn * 4 + r) * 1024]);      \
  } while (0)

  constexpr int NT = KDIM / 64;
  STAGE(0, 0);
  asm volatile("s_waitcnt vmcnt(0)" ::: "memory");
  __builtin_amdgcn_s_barrier();

#pragma unroll
  for (int kt = 0; kt < NT; ++kt) {
    const int cur = kt & 1;
    if (kt + 1 < NT) {
      STAGE(cur ^ 1, (kt + 1) * 64);  // next-buffer loads stay in flight across barrier
      if (wn < 4) asm volatile("s_waitcnt vmcnt(5)" ::: "memory");
      else        asm volatile("s_waitcnt vmcnt(4)" ::: "memory");
    } else {
      asm volatile("s_waitcnt vmcnt(0)" ::: "memory");
    }
    __builtin_amdgcn_s_barrier();        // buf[cur] staged by ALL waves
    __builtin_amdgcn_sched_barrier(0);
    i32x4 af[4];
#pragma unroll
    for (int fm = 0; fm < 4; ++fm)
      af[fm] = *(const i32x4*)&u.st[cur].A[(fm * 16 + lr) * 64 + kg * 16];
#pragma unroll
    for (int fn = 0; fn < 4; ++fn) {
      i32x4 bf = *(const i32x4*)&u.st[cur].B[(wn * 64 + fn * 16 + lr) * 64 + kg * 16];
#pragma unroll
      for (int fm = 0; fm < 4; ++fm)
        acc[fm][fn] = __builtin_amdgcn_mfma_i32_16x16x64_i8(af[fm], bf, acc[fm][fn], 0, 0, 0);
    }
    __builtin_amdgcn_sched_barrier(0);
    __builtin_amdgcn_s_barrier();        // buf[cur] free for next STAGE (no drain)
  }
#undef STAGE

  // ---- epilogue: acc element j -> row fm*16+kg*4+j, col wn*64+fn*16+lr
  const float wsv_ = wS[0];

  if constexpr (L1) {
    f32x4 fa[4][4];
#pragma unroll
    for (int fm = 0; fm < 4; ++fm) {
      float sc[4];
#pragma unroll
      for (int j = 0; j < 4; ++j) sc[j] = rowR[fm * 16 + kg * 4 + j] * wsv_;
#pragma unroll
      for (int fn = 0; fn < 4; ++fn) {
        const float bb = biasS[wn * 64 + fn * 16 + lr];
#pragma unroll
        for (int j = 0; j < 4; ++j)
          fa[fm][fn][j] = fmaxf((float)acc[fm][fn][j] * sc[j] + bb, 0.0f);
      }
    }
#pragma unroll
    for (int fm = 0; fm < 4; ++fm)
#pragma unroll
      for (int j = 0; j < 4; ++j) {
        float ss = 0.f, mx = 0.f;
#pragma unroll
        for (int fn = 0; fn < 4; ++fn) { float h = fa[fm][fn][j]; ss += h * h; mx = fmaxf(mx, h); }
#pragma unroll
        for (int m = 8; m >= 1; m >>= 1) { ss += __shfl_xor(ss, m); mx = fmaxf(mx, __shfl_xor(mx, m)); }
        if (lr == 0) {
          int rl = fm * 16 + kg * 4 + j;
          u.ep.sq[rl][wn] = ss;
          u.ep.mx[rl][wn] = mx;
        }
      }
    __syncthreads();
#pragma unroll
    for (int fm = 0; fm < 4; ++fm)
#pragma unroll
      for (int j = 0; j < 4; ++j) {
        const int rl = fm * 16 + kg * 4 + j;
        float sst = 0.f, mxt = 0.f;
#pragma unroll
        for (int w = 0; w < 8; ++w) {
          sst += u.ep.sq[rl][w];
          mxt = fmaxf(mxt, u.ep.mx[rl][w]);
        }
        float inv = 1.0f / sqrtf(sst * (1.0f / 512.0f) + 1e-6f);
        float amax = fmaxf(mxt * inv, 1e-5f);
        float s = 127.0f / amax;
        if (lr == 0 && wn == 0) rActOut[row0 + rl] = amax / 127.0f;
#pragma unroll
        for (int fn = 0; fn < 4; ++fn) {
          float xn = fa[fm][fn][j] * inv;
          int qi = (int)fminf(fmaxf(rintf(xn * s), -128.0f), 127.0f);
          XqOut[(row0 + rl) * 512 + wn * 64 + fn * 16 + lr] = (char)qi;
        }
      }
  } else {
    float colsum[4] = {0.f, 0.f, 0.f, 0.f};
#pragma unroll
    for (int fm = 0; fm < 4; ++fm) {
      float sc[4];
#pragma unroll
      for (int j = 0; j < 4; ++j) sc[j] = rowR[fm * 16 + kg * 4 + j] * wsv_;
#pragma unroll
      for (int fn = 0; fn < 4; ++fn) {
        const int col = wn * 64 + fn * 16 + lr;
        const float bb = biasS[col];
#pragma unroll
        for (int j = 0; j < 4; ++j) {
          const size_t rg = row0 + fm * 16 + kg * 4 + j;
          float v = (float)acc[fm][fn][j] * sc[j] + bb;
          float like = 1.0f / (1.0f + expf(-v));
          float un = prior[rg * 512 + col] * like;   // exact f32 for the normalizer
          if constexpr (BF) unBf[rg * 512 + col] = f2bf(un);
          else              outUn[rg * 512 + col] = un;
          colsum[fn] += un;
        }
      }
    }
#pragma unroll
    for (int fn = 0; fn < 4; ++fn) {
      colsum[fn] += __shfl_xor(colsum[fn], 16);
      colsum[fn] += __shfl_xor(colsum[fn], 32);
    }
    if (lane < 16) {
#pragma unroll
      for (int fn = 0; fn < 4; ++fn) normPart[wn * 64 + fn * 16 + lane] = colsum[fn];
    }
    __syncthreads();
    partG[(size_t)blockIdx.x * 512 + tid] = normPart[tid];
  }
}

// ---------------- normalization over S ----------------
__global__ void kNorm1(const float* __restrict__ partG, float* __restrict__ normA) {
  const int b = blockIdx.x, f = threadIdx.x;
  float s = 0.f;
#pragma unroll
  for (int i = 0; i < 16; ++i) s += partG[(size_t)(b * 16 + i) * 512 + f];
  normA[b * 512 + f] = fmaxf(s, 1e-10f);
}

// f32 in-place path (fallback)
__global__ void kNorm2(float* __restrict__ out, const float* __restrict__ normA) {
  const size_t i4 = (size_t)blockIdx.x * blockDim.x + threadIdx.x;
  f32x4 v = ((const f32x4*)out)[i4];
  const int f4 = (int)(i4 & 127);
  const int b = (int)(i4 >> 17);
  f32x4 n = ((const f32x4*)normA)[b * 128 + f4];
  v[0] /= n[0]; v[1] /= n[1]; v[2] /= n[2]; v[3] /= n[3];
  ((f32x4*)out)[i4] = v;
}

// bf16-un path, 16B-contiguous lanes: two groups of 4 elems per thread.
// Loads: 8B/lane contiguous (512B/inst). Stores: 16B/lane contiguous (1KB/inst).
__global__ void kNorm2bf(const unsigned short* __restrict__ unBf,
                         float* __restrict__ out, const float* __restrict__ normA) {
  const size_t base = (size_t)blockIdx.x * 2048;  // 8192 blocks x 256 thr x 8 elems
  const int l = threadIdx.x;
#pragma unroll
  for (int g = 0; g < 2; ++g) {
    const size_t e0 = base + g * 1024 + 4 * (size_t)l;
    i32x2 raw = *(const i32x2*)(unBf + e0);       // 4 bf16
    const int b = (int)(e0 >> 19);                // 512*1024 elems per batch
    const int f0 = (int)(e0 & 511);
    f32x4 n = *(const f32x4*)(normA + b * 512 + f0);
    f32x4 o;
#pragma unroll
    for (int k = 0; k < 2; ++k) {
      unsigned wrd = (unsigned)raw[k];
      union { unsigned u; float f; } lo, hi;
      lo.u = (wrd & 0xffffu) << 16;
      hi.u = (wrd & 0xffff0000u);
      o[k * 2] = lo.f; o[k * 2 + 1] = hi.f;
    }
    o[0] /= n[0]; o[1] /= n[1]; o[2] /= n[2]; o[3] /= n[3];
    *(f32x4*)(out + e0) = o;
  }
}

// ---------------- launcher ----------------
extern "C" void kernel_launch(void* const* d_in, const int* in_sizes, int n_in,
                              void* d_out, int out_size, void* d_ws, size_t ws_size,
                              hipStream_t stream) {
  const float* evid  = (const float*)d_in[0];   // [32,1024,512]
  const float* prior = (const float*)d_in[1];   // [32,1024,512]
  const float* W1    = (const float*)d_in[2];   // [512,1024]
  const float* b1    = (const float*)d_in[3];   // [512]
  const float* W2    = (const float*)d_in[4];   // [512,512]
  const float* b2    = (const float*)d_in[5];   // [512]
  float* out = (float*)d_out;

  char* ws = (char*)d_ws;
  char*   X2q   = ws;                              // 16,777,216 B (i8 [32768][512])
  char*   W1q   = ws + 16777216;                   //    524,288 B
  char*   W2q   = ws + 17301504;                   //    262,144 B
  float*  r1    = (float*)(ws + 17563648);         //    131,072 B
  float*  r2    = (float*)(ws + 17694720);         //    131,072 B
  double* part  = (double*)(ws + 17825792);        //      4,096 B
  float*  wsv   = (float*)(ws + 17829888);         //        256 B
  float*  partG = (float*)(ws + 17830144);         //  1,048,576 B
  float*  normA = (float*)(ws + 18878720);         //     65,536 B   -> 18,944,256 B
  unsigned short* unBf = (unsigned short*)(ws + 18944256);  // 33,554,432 B (optional)
  const bool useBf = ws_size >= (size_t)18944256 + 33554432;

  // X1q (i8 [32768][1024] = 33.5 MB) lives in d_out (67 MB); dead before un/out writes.
  char* X1q = (char*)d_out;

  kWabs<<<512, 256, 0, stream>>>(W1, W2, part);
  kWfin<<<2, 256, 0, stream>>>(part, wsv);
  kWq<<<3072, 256, 0, stream>>>(W1, W2, wsv, W1q, W2q);
  kQ1<<<4096, 512, 0, stream>>>(prior, evid, X1q, r1);
  kGemm<1024, true, false><<<512, 512, 0, stream>>>(X1q, W1q, b1, r1, wsv + 0,
                                                    X2q, r2, nullptr, nullptr, nullptr, nullptr);
  if (useBf) {
    kGemm<512, false, true><<<512, 512, 0, stream>>>(X2q, W2q, b2, r2, wsv + 1,
                                                     nullptr, nullptr, prior, nullptr, unBf, partG);
    kNorm1<<<32, 512, 0, stream>>>(partG, normA);
    kNorm2bf<<<8192, 256, 0, stream>>>(unBf, out, normA);
  } else {
    kGemm<512, false, false><<<512, 512, 0, stream>>>(X2q, W2q, b2, r2, wsv + 1,
                                                      nullptr, nullptr, prior, out, nullptr, partG);
    kNorm1<<<32, 512, 0, stream>>>(partG, normA);
    kNorm2<<<16384, 256, 0, stream>>>(out, normA);
  }
}

// Round 17
// 122.982 us; speedup vs baseline: 1.2555x; 1.0325x over previous
//
#include <hip/hip_runtime.h>
#include <math.h>

typedef __attribute__((ext_vector_type(4))) int i32x4;
typedef __attribute__((ext_vector_type(2))) int i32x2;
typedef __attribute__((ext_vector_type(4))) float f32x4;

#define GLOAD_LDS16(g, l)                                          \
  __builtin_amdgcn_global_load_lds(                                \
      (const __attribute__((address_space(1))) void*)(g),          \
      (__attribute__((address_space(3))) void*)(l), 16, 0, 0)

static __device__ __forceinline__ unsigned short f2bf(float f) {
  union { float f; unsigned u; } c; c.f = f;
  unsigned u = c.u;
  return (unsigned short)((u + 0x7fffu + ((u >> 16) & 1u)) >> 16);  // RNE
}

// ---------------- weight mean|.| partials (W1 blocks 0-255, W2 blocks 256-511) ----------
__global__ void kWabs(const float* __restrict__ w1, const float* __restrict__ w2,
                      double* __restrict__ part) {
  const bool second = blockIdx.x >= 256;
  const float* w = second ? w2 : w1;
  const int n = second ? 262144 : 524288;
  int t = (blockIdx.x & 255) * 256 + threadIdx.x;
  double s = 0.0;
  for (int i = t; i < n; i += 65536) s += (double)fabsf(w[i]);
#pragma unroll
  for (int m = 32; m >= 1; m >>= 1) s += __shfl_xor(s, m);
  __shared__ double sd[4];
  int lane = threadIdx.x & 63, wid = threadIdx.x >> 6;
  if (lane == 0) sd[wid] = s;
  __syncthreads();
  if (threadIdx.x == 0) part[blockIdx.x] = (sd[0] + sd[1]) + (sd[2] + sd[3]);
}

// ---------------- MERGED: input RMSNorm+quant (blocks 0-4095) | weight quant (4096-5631) --
// kQ1 body identical to round 16. Weight blocks re-reduce the 512 f64 partials from L2
// (kWfin's exact order -> bit-identical scale), quantize 512 weights each, and blocks
// 4096/5120 publish wsv[0]/wsv[1] for the GEMM epilogues. Weight work rides in kQ1's
// memory shadow instead of serializing ahead of it (was 2 extra dispatches).
__global__ __launch_bounds__(512) void kQW(
    const float* __restrict__ prior, const float* __restrict__ evid,
    char* __restrict__ Xq, float* __restrict__ rAct,
    const float* __restrict__ w1, const float* __restrict__ w2,
    const double* __restrict__ part, float* __restrict__ wsv,
    char* __restrict__ wq1, char* __restrict__ wq2) {
  if (blockIdx.x < 4096) {
    // ---- input RMSNorm + absmax quant: wave-per-row, 16B-contiguous lanes ----
    const int w = threadIdx.x >> 6;
    const int l = threadIdx.x & 63;
    const size_t row = (size_t)blockIdx.x * 8 + w;
    const f32x4* pp = (const f32x4*)(prior + row * 512);
    const f32x4* pe = (const f32x4*)(evid + row * 512);
    f32x4 x[4];
    x[0] = pp[l];
    x[1] = pp[64 + l];
    x[2] = pe[l];
    x[3] = pe[64 + l];
    float ss = 0.f, mx = 0.f;
#pragma unroll
    for (int v = 0; v < 4; ++v)
#pragma unroll
      for (int i = 0; i < 4; ++i) { float f = x[v][i]; ss += f * f; mx = fmaxf(mx, fabsf(f)); }
#pragma unroll
    for (int m = 32; m >= 1; m >>= 1) { ss += __shfl_xor(ss, m); mx = fmaxf(mx, __shfl_xor(mx, m)); }
    const float inv = 1.0f / sqrtf(ss * (1.0f / 1024.0f) + 1e-6f);
    const float amax = fmaxf(mx * inv, 1e-5f);
    const float s = 127.0f / amax;
    int pk[4];
#pragma unroll
    for (int v = 0; v < 4; ++v) {
      int p = 0;
#pragma unroll
      for (int i = 0; i < 4; ++i) {
        int qi = (int)fminf(fmaxf(rintf(x[v][i] * inv * s), -128.0f), 127.0f);
        p |= (qi & 255) << (8 * i);
      }
      pk[v] = p;
    }
    char* dst = Xq + row * 1024;
    *(int*)(dst + 4 * l)       = pk[0];
    *(int*)(dst + 256 + 4 * l) = pk[1];
    *(int*)(dst + 512 + 4 * l) = pk[2];
    *(int*)(dst + 768 + 4 * l) = pk[3];
    if (l == 0) rAct[row] = amax / 127.0f;
  } else {
    // ---- weight quantization ----
    const int wb = blockIdx.x - 4096;        // 0..1535: W1 = 0..1023, W2 = 1024..1535
    const bool second = wb >= 1024;
    const float* w = second ? w2 : w1;
    char* wq = second ? wq2 : wq1;
    const double* p = part + (second ? 256 : 0);
    const double nels = second ? 262144.0 : 524288.0;
    __shared__ double sd[4];
    __shared__ float scaleS;
    const int tid = threadIdx.x;
    if (tid < 256) {  // kWfin's exact reduce: 4 full waves
      double s = p[tid];
#pragma unroll
      for (int m = 32; m >= 1; m >>= 1) s += __shfl_xor(s, m);
      int lane = tid & 63, wid = tid >> 6;
      if (lane == 0) sd[wid] = s;
    }
    __syncthreads();
    if (tid == 0) {
      double tot = (sd[0] + sd[1]) + (sd[2] + sd[3]);
      float sv = fmaxf((float)(tot / nels), 1e-5f);  // = 1/scale_w
      scaleS = 1.0f / sv;
      if (wb == 0) wsv[0] = sv;
      if (wb == 1024) wsv[1] = sv;
    }
    __syncthreads();
    const float scale = scaleS;
    const int i = (second ? wb - 1024 : wb) * 512 + tid;
    float q = fminf(fmaxf(rintf(w[i] * scale), -1.0f), 1.0f);
    wq[i] = (char)(int)q;
  }
}

// ---------------- fused BitLinear GEMM, i8 MFMA, 64x512 tile, counted-vmcnt pipeline ----
template <int KDIM, bool L1, bool BF>
__global__ __launch_bounds__(512, 4) void kGemm(
    const char* __restrict__ Xq, const char* __restrict__ Wq,
    const float* __restrict__ biasG, const float* __restrict__ rAct,
    const float* __restrict__ wS,
    char* __restrict__ XqOut, float* __restrict__ rActOut,
    const float* __restrict__ prior, float* __restrict__ outUn,
    unsigned short* __restrict__ unBf, float* __restrict__ partG) {
  struct Stage { char A[4096]; char B[32768]; };
  __shared__ __align__(16) union {
    Stage st[2];                                     // 73,728 B double buffer
    struct { float sq[64][8]; float mx[64][8]; } ep; // L1 epilogue overlay
  } u;
  __shared__ float rowR[64];
  __shared__ float biasS[512];
  __shared__ float normPart[512];

  const int tid = threadIdx.x;
  const int lane = tid & 63;
  const int wn = tid >> 6;   // wave -> 64-col strip (0..7)
  const int lr = lane & 15;
  const int kg = lane >> 4;  // 0..3
  const size_t row0 = (size_t)blockIdx.x * 64;

  if (tid < 64) rowR[tid] = rAct[row0 + tid];
  biasS[tid] = biasG[tid];

  i32x4 acc[4][4];
#pragma unroll
  for (int a = 0; a < 4; ++a)
#pragma unroll
    for (int b = 0; b < 4; ++b) acc[a][b] = (i32x4){0, 0, 0, 0};

  const int lrow = lane >> 2;       // row within a 16-row chunk
  const int lkb = (lane & 3) * 16;  // 16B k-slice within a 64B row

  const char* gA = Xq + (row0 + (wn & 3) * 16 + lrow) * (size_t)KDIM + lkb;
  const char* gB[4];
#pragma unroll
  for (int r = 0; r < 4; ++r)
    gB[r] = Wq + ((wn * 4 + r) * 16 + lrow) * (size_t)KDIM + lkb;

#define STAGE(b, k0)                                                   \
  do {                                                                 \
    if (wn < 4) GLOAD_LDS16(gA + (k0), &u.st[b].A[(wn & 3) * 1024]);   \
    _Pragma("unroll")                                                  \
    for (int r = 0; r < 4; ++r)                                        \
      GLOAD_LDS16(gB[r] + (k0), &u.st[b].B[(wn * 4 + r) * 1024]);      \
  } while (0)

  constexpr int NT = KDIM / 64;
  STAGE(0, 0);
  asm volatile("s_waitcnt vmcnt(0)" ::: "memory");
  __builtin_amdgcn_s_barrier();

#pragma unroll
  for (int kt = 0; kt < NT; ++kt) {
    const int cur = kt & 1;
    if (kt + 1 < NT) {
      STAGE(cur ^ 1, (kt + 1) * 64);  // next-buffer loads stay in flight across barrier
      if (wn < 4) asm volatile("s_waitcnt vmcnt(5)" ::: "memory");
      else        asm volatile("s_waitcnt vmcnt(4)" ::: "memory");
    } else {
      asm volatile("s_waitcnt vmcnt(0)" ::: "memory");
    }
    __builtin_amdgcn_s_barrier();        // buf[cur] staged by ALL waves
    __builtin_amdgcn_sched_barrier(0);
    i32x4 af[4];
#pragma unroll
    for (int fm = 0; fm < 4; ++fm)
      af[fm] = *(const i32x4*)&u.st[cur].A[(fm * 16 + lr) * 64 + kg * 16];
#pragma unroll
    for (int fn = 0; fn < 4; ++fn) {
      i32x4 bf = *(const i32x4*)&u.st[cur].B[(wn * 64 + fn * 16 + lr) * 64 + kg * 16];
#pragma unroll
      for (int fm = 0; fm < 4; ++fm)
        acc[fm][fn] = __builtin_amdgcn_mfma_i32_16x16x64_i8(af[fm], bf, acc[fm][fn], 0, 0, 0);
    }
    __builtin_amdgcn_sched_barrier(0);
    __builtin_amdgcn_s_barrier();        // buf[cur] free for next STAGE (no drain)
  }
#undef STAGE

  // ---- epilogue: acc element j -> row fm*16+kg*4+j, col wn*64+fn*16+lr
  const float wsv_ = wS[0];

  if constexpr (L1) {
    f32x4 fa[4][4];
#pragma unroll
    for (int fm = 0; fm < 4; ++fm) {
      float sc[4];
#pragma unroll
      for (int j = 0; j < 4; ++j) sc[j] = rowR[fm * 16 + kg * 4 + j] * wsv_;
#pragma unroll
      for (int fn = 0; fn < 4; ++fn) {
        const float bb = biasS[wn * 64 + fn * 16 + lr];
#pragma unroll
        for (int j = 0; j < 4; ++j)
          fa[fm][fn][j] = fmaxf((float)acc[fm][fn][j] * sc[j] + bb, 0.0f);
      }
    }
#pragma unroll
    for (int fm = 0; fm < 4; ++fm)
#pragma unroll
      for (int j = 0; j < 4; ++j) {
        float ss = 0.f, mx = 0.f;
#pragma unroll
        for (int fn = 0; fn < 4; ++fn) { float h = fa[fm][fn][j]; ss += h * h; mx = fmaxf(mx, h); }
#pragma unroll
        for (int m = 8; m >= 1; m >>= 1) { ss += __shfl_xor(ss, m); mx = fmaxf(mx, __shfl_xor(mx, m)); }
        if (lr == 0) {
          int rl = fm * 16 + kg * 4 + j;
          u.ep.sq[rl][wn] = ss;
          u.ep.mx[rl][wn] = mx;
        }
      }
    __syncthreads();
#pragma unroll
    for (int fm = 0; fm < 4; ++fm)
#pragma unroll
      for (int j = 0; j < 4; ++j) {
        const int rl = fm * 16 + kg * 4 + j;
        float sst = 0.f, mxt = 0.f;
#pragma unroll
        for (int w = 0; w < 8; ++w) {
          sst += u.ep.sq[rl][w];
          mxt = fmaxf(mxt, u.ep.mx[rl][w]);
        }
        float inv = 1.0f / sqrtf(sst * (1.0f / 512.0f) + 1e-6f);
        float amax = fmaxf(mxt * inv, 1e-5f);
        float s = 127.0f / amax;
        if (lr == 0 && wn == 0) rActOut[row0 + rl] = amax / 127.0f;
#pragma unroll
        for (int fn = 0; fn < 4; ++fn) {
          float xn = fa[fm][fn][j] * inv;
          int qi = (int)fminf(fmaxf(rintf(xn * s), -128.0f), 127.0f);
          XqOut[(row0 + rl) * 512 + wn * 64 + fn * 16 + lr] = (char)qi;
        }
      }
  } else {
    float colsum[4] = {0.f, 0.f, 0.f, 0.f};
#pragma unroll
    for (int fm = 0; fm < 4; ++fm) {
      float sc[4];
#pragma unroll
      for (int j = 0; j < 4; ++j) sc[j] = rowR[fm * 16 + kg * 4 + j] * wsv_;
#pragma unroll
      for (int fn = 0; fn < 4; ++fn) {
        const int col = wn * 64 + fn * 16 + lr;
        const float bb = biasS[col];
#pragma unroll
        for (int j = 0; j < 4; ++j) {
          const size_t rg = row0 + fm * 16 + kg * 4 + j;
          float v = (float)acc[fm][fn][j] * sc[j] + bb;
          float like = 1.0f / (1.0f + expf(-v));
          float un = prior[rg * 512 + col] * like;   // exact f32 for the normalizer
          if constexpr (BF) unBf[rg * 512 + col] = f2bf(un);
          else              outUn[rg * 512 + col] = un;
          colsum[fn] += un;
        }
      }
    }
#pragma unroll
    for (int fn = 0; fn < 4; ++fn) {
      colsum[fn] += __shfl_xor(colsum[fn], 16);
      colsum[fn] += __shfl_xor(colsum[fn], 32);
    }
    if (lane < 16) {
#pragma unroll
      for (int fn = 0; fn < 4; ++fn) normPart[wn * 64 + fn * 16 + lane] = colsum[fn];
    }
    __syncthreads();
    partG[(size_t)blockIdx.x * 512 + tid] = normPart[tid];
  }
}

// ---------------- normalization over S ----------------
__global__ void kNorm1(const float* __restrict__ partG, float* __restrict__ normA) {
  const int b = blockIdx.x, f = threadIdx.x;
  float s = 0.f;
#pragma unroll
  for (int i = 0; i < 16; ++i) s += partG[(size_t)(b * 16 + i) * 512 + f];
  normA[b * 512 + f] = fmaxf(s, 1e-10f);
}

// f32 in-place path (fallback)
__global__ void kNorm2(float* __restrict__ out, const float* __restrict__ normA) {
  const size_t i4 = (size_t)blockIdx.x * blockDim.x + threadIdx.x;
  f32x4 v = ((const f32x4*)out)[i4];
  const int f4 = (int)(i4 & 127);
  const int b = (int)(i4 >> 17);
  f32x4 n = ((const f32x4*)normA)[b * 128 + f4];
  v[0] /= n[0]; v[1] /= n[1]; v[2] /= n[2]; v[3] /= n[3];
  ((f32x4*)out)[i4] = v;
}

// bf16-un path, 16B-contiguous lanes
__global__ void kNorm2bf(const unsigned short* __restrict__ unBf,
                         float* __restrict__ out, const float* __restrict__ normA) {
  const size_t base = (size_t)blockIdx.x * 2048;  // 8192 blocks x 256 thr x 8 elems
  const int l = threadIdx.x;
#pragma unroll
  for (int g = 0; g < 2; ++g) {
    const size_t e0 = base + g * 1024 + 4 * (size_t)l;
    i32x2 raw = *(const i32x2*)(unBf + e0);       // 4 bf16
    const int b = (int)(e0 >> 19);                // 512*1024 elems per batch
    const int f0 = (int)(e0 & 511);
    f32x4 n = *(const f32x4*)(normA + b * 512 + f0);
    f32x4 o;
#pragma unroll
    for (int k = 0; k < 2; ++k) {
      unsigned wrd = (unsigned)raw[k];
      union { unsigned u; float f; } lo, hi;
      lo.u = (wrd & 0xffffu) << 16;
      hi.u = (wrd & 0xffff0000u);
      o[k * 2] = lo.f; o[k * 2 + 1] = hi.f;
    }
    o[0] /= n[0]; o[1] /= n[1]; o[2] /= n[2]; o[3] /= n[3];
    *(f32x4*)(out + e0) = o;
  }
}

// ---------------- launcher ----------------
extern "C" void kernel_launch(void* const* d_in, const int* in_sizes, int n_in,
                              void* d_out, int out_size, void* d_ws, size_t ws_size,
                              hipStream_t stream) {
  const float* evid  = (const float*)d_in[0];   // [32,1024,512]
  const float* prior = (const float*)d_in[1];   // [32,1024,512]
  const float* W1    = (const float*)d_in[2];   // [512,1024]
  const float* b1    = (const float*)d_in[3];   // [512]
  const float* W2    = (const float*)d_in[4];   // [512,512]
  const float* b2    = (const float*)d_in[5];   // [512]
  float* out = (float*)d_out;

  char* ws = (char*)d_ws;
  char*   X2q   = ws;                              // 16,777,216 B (i8 [32768][512])
  char*   W1q   = ws + 16777216;                   //    524,288 B
  char*   W2q   = ws + 17301504;                   //    262,144 B
  float*  r1    = (float*)(ws + 17563648);         //    131,072 B
  float*  r2    = (float*)(ws + 17694720);         //    131,072 B
  double* part  = (double*)(ws + 17825792);        //      4,096 B
  float*  wsv   = (float*)(ws + 17829888);         //        256 B
  float*  partG = (float*)(ws + 17830144);         //  1,048,576 B
  float*  normA = (float*)(ws + 18878720);         //     65,536 B   -> 18,944,256 B
  unsigned short* unBf = (unsigned short*)(ws + 18944256);  // 33,554,432 B (optional)
  const bool useBf = ws_size >= (size_t)18944256 + 33554432;

  // X1q (i8 [32768][1024] = 33.5 MB) lives in d_out (67 MB); dead before un/out writes.
  char* X1q = (char*)d_out;

  kWabs<<<512, 256, 0, stream>>>(W1, W2, part);
  kQW<<<5632, 512, 0, stream>>>(prior, evid, X1q, r1, W1, W2, part, wsv, W1q, W2q);
  kGemm<1024, true, false><<<512, 512, 0, stream>>>(X1q, W1q, b1, r1, wsv + 0,
                                                    X2q, r2, nullptr, nullptr, nullptr, nullptr);
  if (useBf) {
    kGemm<512, false, true><<<512, 512, 0, stream>>>(X2q, W2q, b2, r2, wsv + 1,
                                                     nullptr, nullptr, prior, nullptr, unBf, partG);
    kNorm1<<<32, 512, 0, stream>>>(partG, normA);
    kNorm2bf<<<8192, 256, 0, stream>>>(unBf, out, normA);
  } else {
    kGemm<512, false, false><<<512, 512, 0, stream>>>(X2q, W2q, b2, r2, wsv + 1,
                                                      nullptr, nullptr, prior, out, nullptr, partG);
    kNorm1<<<32, 512, 0, stream>>>(partG, normA);
    kNorm2<<<16384, 256, 0, stream>>>(out, normA);
  }
}